// Round 5
// baseline (110.379 us; speedup 1.0000x reference)
//
#include <hip/hip_runtime.h>

// Problem constants (fixed by the reference harness).
constexpr int Nn   = 100000;   // nodes
constexpr int Ee   = 1600000;  // edges  (divisible by 4)
constexpr int D    = 128;      // feature dim
constexpr int NT   = 18;       // 2 + 16 target entries (duplicates allowed)

// Capacities (expected: |L2|~290, |S|~310, |L1|~5000)
constexpr int CAPS = 1024;
constexpr int CAP2 = 1024;
constexpr int CAP1 = 8192;

constexpr int BMW = 3136;      // bitmap words: >= ceil(Nn/32)=3125, %4==0

// hdr slots
#define HDR_CNTS  1
#define HDR_CNTL1 2
#define HDR_CNTL2 3

// ---- workspace byte offsets (all 16B aligned) ----
constexpr size_t OFF_HDR   = 0;          // int[64]          256   (zeroed)
constexpr size_t OFF_MARKS = 256;        // int[Nn]          400000
constexpr size_t OFF_BMS   = 400256;     // u32[BMW]         12544
constexpr size_t OFF_A1    = 412800;     // f32[CAPS*D]      524288
constexpr size_t OFF_A2    = 937088;     // f32[32*D]        16384
constexpr size_t ZERO_BYTES= 953472;     // zero everything above (÷16 ok)
constexpr size_t OFF_SLIST = 953472;     // int[CAPS]        4096
constexpr size_t OFF_L2    = 957568;     // int[CAP2*3]      12288
constexpr size_t OFF_L1    = 969856;     // int[CAP1*3]      98304
constexpr size_t OFF_HS    = 1068160;    // f32[CAPS*D]      524288
constexpr size_t OFF_EMB   = 1592448;    // f32[32*D]        16384
constexpr size_t WS_NEED   = 1608832;

__global__ void k_zero(float4* p, int n4) {
    int i = blockIdx.x * blockDim.x + threadIdx.x;
    int stride = gridDim.x * blockDim.x;
    for (; i < n4; i += stride) p[i] = float4{0.f, 0.f, 0.f, 0.f};
}

// Scan all edges; each block builds an LDS bitmap of the 18 target ids, tests
// dst against it (1 LDS read + bit test per edge). On hit: first-occurrence
// slot via tiny LDS search, record (src,e,slot) in L2, mark src. Block 0 also
// marks the targets themselves as needing h.
__global__ void __launch_bounds__(256)
k_scanT(const int* __restrict__ src, const int* __restrict__ dst,
        const int* __restrict__ cur, const int* __restrict__ des,
        const int* __restrict__ nbr,
        int* __restrict__ hdr, int* __restrict__ markS, int* __restrict__ L2) {
    __shared__ unsigned bm[BMW];
    __shared__ int sT[NT];
    int t = threadIdx.x;
    for (int w = t; w < BMW; w += 256) bm[w] = 0u;
    if (t < NT) {
        int v = (t == 0) ? cur[0] : (t == 1) ? des[0] : nbr[t - 2];
        sT[t] = v;
        if (blockIdx.x == 0) markS[v] = 1;   // targets need h too
    }
    __syncthreads();
    if (t < NT) atomicOr(&bm[(unsigned)sT[t] >> 5], 1u << (sT[t] & 31));
    __syncthreads();
    int stride = gridDim.x * blockDim.x;
    for (int q = blockIdx.x * blockDim.x + t; q < Ee / 4; q += stride) {
        int4 d4 = reinterpret_cast<const int4*>(dst)[q];
        int ds[4] = {d4.x, d4.y, d4.z, d4.w};
        #pragma unroll
        for (int j = 0; j < 4; ++j) {
            int d = ds[j];
            if ((bm[(unsigned)d >> 5] >> (d & 31)) & 1u) {
                int slot = 0;
                while (sT[slot] != d) ++slot;   // first occurrence, always found
                int e = q * 4 + j;
                int s = src[e];
                int idx = atomicAdd(&hdr[HDR_CNTL2], 1);
                if (idx < CAP2) { L2[3*idx] = s; L2[3*idx+1] = e; L2[3*idx+2] = slot; }
                markS[s] = 1;  // benign same-value race
            }
        }
    }
}

// Assign compact slots to marked nodes (markS: 1 -> 2+slot); build global
// S-bitmap for the second edge scan.
__global__ void k_stageC(int* __restrict__ markS, int* __restrict__ hdr,
                         int* __restrict__ Slist, unsigned* __restrict__ bmS) {
    int i = blockIdx.x * blockDim.x + threadIdx.x;
    if (i >= Nn / 4) return;
    int4 m4 = reinterpret_cast<const int4*>(markS)[i];
    int ms[4] = {m4.x, m4.y, m4.z, m4.w};
    int v0 = i * 4;
    #pragma unroll
    for (int j = 0; j < 4; ++j) {
        if (ms[j] == 1) {
            int s = atomicAdd(&hdr[HDR_CNTS], 1);
            if (s < CAPS) {
                int v = v0 + j;
                markS[v] = 2 + s;
                Slist[s] = v;
                atomicOr(&bmS[(unsigned)v >> 5], 1u << (v & 31));
            }
        }
    }
}

// Scan all edges; membership test against LDS copy of the S-bitmap. Only hits
// (~0.3%) read markS for the slot and append to L1.
__global__ void __launch_bounds__(256)
k_scanS(const int* __restrict__ src, const int* __restrict__ dst,
        const int* __restrict__ markS, const unsigned* __restrict__ bmS,
        int* __restrict__ hdr, int* __restrict__ L1) {
    __shared__ unsigned bm[BMW];
    int t = threadIdx.x;
    const uint4* g = reinterpret_cast<const uint4*>(bmS);
    for (int w = t; w < BMW / 4; w += 256) reinterpret_cast<uint4*>(bm)[w] = g[w];
    __syncthreads();
    int stride = gridDim.x * blockDim.x;
    for (int q = blockIdx.x * blockDim.x + t; q < Ee / 4; q += stride) {
        int4 d4 = reinterpret_cast<const int4*>(dst)[q];
        int ds[4] = {d4.x, d4.y, d4.z, d4.w};
        #pragma unroll
        for (int j = 0; j < 4; ++j) {
            int d = ds[j];
            if ((bm[(unsigned)d >> 5] >> (d & 31)) & 1u) {
                int e = q * 4 + j;
                int v = markS[d];
                if (v >= 2) {
                    int idx = atomicAdd(&hdr[HDR_CNTL1], 1);
                    if (idx < CAP1) { L1[3*idx] = src[e]; L1[3*idx+1] = e; L1[3*idx+2] = v - 2; }
                }
            }
        }
    }
}

// Aggregate messages: A[slot][d] += relu(X[row][d] + ea[e]*We[d] + be[d]).
// If remap != null, row = remap[src]-2 (compacted Hs rows), else row = src.
__global__ void k_aggr(const float* __restrict__ X, const float* __restrict__ ea,
                       const float* __restrict__ We, const float* __restrict__ be,
                       const int* __restrict__ L, int* __restrict__ hdr,
                       int cntIdx, int cap, const int* __restrict__ remap,
                       float* __restrict__ A) {
    int tid = blockIdx.x * blockDim.x + threadIdx.x;
    int i = tid >> 5;  // 32 threads per edge, 4 dims each
    int cnt = hdr[cntIdx];
    if (cnt > cap) cnt = cap;
    if (i >= cnt) return;
    int s    = L[3*i + 0];
    int e    = L[3*i + 1];
    int slot = L[3*i + 2];
    if (remap) {
        s = remap[s] - 2;
        if ((unsigned)s >= (unsigned)CAPS) return;
    }
    int d0 = (tid & 31) << 2;
    float a = ea[e];
    float4 xv = *reinterpret_cast<const float4*>(&X[(size_t)s * D + d0]);
    float4 wv = *reinterpret_cast<const float4*>(&We[d0]);
    float4 bv = *reinterpret_cast<const float4*>(&be[d0]);
    float* Ar = &A[(size_t)slot * D + d0];
    atomicAdd(Ar + 0, fmaxf(fmaf(a, wv.x, bv.x) + xv.x, 0.f));
    atomicAdd(Ar + 1, fmaxf(fmaf(a, wv.y, bv.y) + xv.y, 0.f));
    atomicAdd(Ar + 2, fmaxf(fmaf(a, wv.z, bv.z) + xv.z, 0.f));
    atomicAdd(Ar + 3, fmaxf(fmaf(a, wv.w, bv.w) + xv.w, 0.f));
}

// conv1 MLP per S-node: Hs[b] = relu( relu((x[node]+A1[b])@W1 + b1) @ W2 + b2 )
__global__ void k_mlpS(const float* __restrict__ x, const float* __restrict__ A,
                       const int* __restrict__ Slist, const int* __restrict__ hdr,
                       const float* __restrict__ W1, const float* __restrict__ b1,
                       const float* __restrict__ W2, const float* __restrict__ b2,
                       float* __restrict__ Hs) {
    __shared__ float buf[D];
    __shared__ float hid[D];
    int b = blockIdx.x;
    int cnt = hdr[HDR_CNTS];
    if (cnt > CAPS) cnt = CAPS;
    if (b >= cnt) return;
    int t = threadIdx.x;  // 128 threads
    int node = Slist[b];
    buf[t] = x[(size_t)node * D + t] + A[(size_t)b * D + t];
    __syncthreads();
    float acc = b1[t];
    #pragma unroll 8
    for (int k = 0; k < D; ++k) acc = fmaf(buf[k], W1[k * D + t], acc);
    hid[t] = fmaxf(acc, 0.f);
    __syncthreads();
    float acc2 = b2[t];
    #pragma unroll 8
    for (int k = 0; k < D; ++k) acc2 = fmaf(hid[k], W2[k * D + t], acc2);
    Hs[(size_t)b * D + t] = fmaxf(acc2, 0.f);
}

// conv2 MLP per target entry (first-occurrence only):
// EMB[b] = relu((Hs[slot]+A2[b])@W1 + b1) @ W2 + b2
__global__ void k_mlpT(const float* __restrict__ Hs, const float* __restrict__ A2,
                       const int* __restrict__ cur, const int* __restrict__ des,
                       const int* __restrict__ nbr, const int* __restrict__ markS,
                       const float* __restrict__ W1, const float* __restrict__ b1,
                       const float* __restrict__ W2, const float* __restrict__ b2,
                       float* __restrict__ EMB) {
    __shared__ float buf[D];
    __shared__ float hid[D];
    __shared__ int sT[NT];
    int b = blockIdx.x;      // 0..17
    int t = threadIdx.x;     // 128 threads
    if (t < NT) sT[t] = (t == 0) ? cur[0] : (t == 1) ? des[0] : nbr[t - 2];
    __syncthreads();
    int node = sT[b];
    for (int j = 0; j < b; ++j) if (sT[j] == node) return;  // duplicate entry
    int ss = markS[node] - 2;
    if ((unsigned)ss >= (unsigned)CAPS) return;
    buf[t] = Hs[(size_t)ss * D + t] + A2[(size_t)b * D + t];
    __syncthreads();
    float acc = b1[t];
    #pragma unroll 8
    for (int k = 0; k < D; ++k) acc = fmaf(buf[k], W1[k * D + t], acc);
    hid[t] = fmaxf(acc, 0.f);
    __syncthreads();
    float acc2 = b2[t];
    #pragma unroll 8
    for (int k = 0; k < D; ++k) acc2 = fmaf(hid[k], W2[k * D + t], acc2);
    EMB[(size_t)b * D + t] = acc2;  // no final relu
}

// Policy head: one block per neighbor k; 512 threads = 4-way split of the
// 384-long dot product, LDS-reduced.
__global__ void __launch_bounds__(512)
k_policy(const float* __restrict__ EMB,
         const int* __restrict__ cur, const int* __restrict__ des,
         const int* __restrict__ nbr,
         const float* __restrict__ Wl1, const float* __restrict__ bl1,
         const float* __restrict__ Wl2, const float* __restrict__ bl2,
         float* __restrict__ out) {
    __shared__ int sT[NT];
    __shared__ float cat[3 * D];
    __shared__ float part[4][D];
    __shared__ float red[D];
    int tid = threadIdx.x;
    int k = blockIdx.x;  // 0..15
    if (tid < NT) sT[tid] = (tid == 0) ? cur[0] : (tid == 1) ? des[0] : nbr[tid - 2];
    __syncthreads();
    // first-occurrence slots (must match k_scanT / k_mlpT semantics)
    int dsl = (sT[1] == sT[0]) ? 0 : 1;
    int nn = sT[2 + k];
    int nsl = 2 + k;
    for (int j = 0; j < 2 + k; ++j) if (sT[j] == nn) { nsl = j; break; }
    if (tid < 3 * D) {
        int seg = tid >> 7;             // 0=curr, 1=dest, 2=nbr
        int t = tid & (D - 1);
        int slot = (seg == 0) ? 0 : (seg == 1) ? dsl : nsl;
        cat[tid] = EMB[slot * D + t];
    }
    __syncthreads();
    int h = tid >> 7;        // 0..3
    int t = tid & (D - 1);
    float acc = 0.f;
    int c0 = h * 96;
    #pragma unroll 8
    for (int c = c0; c < c0 + 96; ++c)
        acc = fmaf(cat[c], Wl1[c * D + t], acc);
    part[h][t] = acc;
    __syncthreads();
    if (tid < D) {
        float v = part[0][t] + part[1][t] + part[2][t] + part[3][t] + bl1[t];
        red[t] = fmaxf(v, 0.f) * Wl2[t];
    }
    __syncthreads();
    for (int s = 64; s > 0; s >>= 1) {
        if (tid < s) red[tid] += red[tid + s];
        __syncthreads();
    }
    if (tid == 0) out[k] = red[0] + bl2[0];
}

extern "C" void kernel_launch(void* const* d_in, const int* in_sizes, int n_in,
                              void* d_out, int out_size, void* d_ws, size_t ws_size,
                              hipStream_t stream) {
    if (ws_size < WS_NEED) return;  // safety guard

    const float* x   = (const float*)d_in[0];
    const int*   ei  = (const int*)d_in[1];   // (2,E) row-major int32
    const int*   cur = (const int*)d_in[2];
    const int*   des = (const int*)d_in[3];
    const int*   nbr = (const int*)d_in[4];
    const float* ea  = (const float*)d_in[5]; // (E,1)
    const float* We1 = (const float*)d_in[6];
    const float* be1 = (const float*)d_in[7];
    const float* W11 = (const float*)d_in[8];
    const float* b11 = (const float*)d_in[9];
    const float* W12 = (const float*)d_in[10];
    const float* b12 = (const float*)d_in[11];
    const float* We2 = (const float*)d_in[12];
    const float* be2 = (const float*)d_in[13];
    const float* W21 = (const float*)d_in[14];
    const float* b21 = (const float*)d_in[15];
    const float* W22 = (const float*)d_in[16];
    const float* b22 = (const float*)d_in[17];
    const float* Wl1 = (const float*)d_in[18];
    const float* bl1 = (const float*)d_in[19];
    const float* Wl2 = (const float*)d_in[20];
    const float* bl2 = (const float*)d_in[21];
    float* out = (float*)d_out;

    char*     ws    = (char*)d_ws;
    int*      hdr   = (int*)(ws + OFF_HDR);
    int*      markS = (int*)(ws + OFF_MARKS);
    unsigned* bmS   = (unsigned*)(ws + OFF_BMS);
    float*    A1    = (float*)(ws + OFF_A1);
    float*    A2    = (float*)(ws + OFF_A2);
    int*      Slist = (int*)(ws + OFF_SLIST);
    int*      L2    = (int*)(ws + OFF_L2);
    int*      L1    = (int*)(ws + OFF_L1);
    float*    Hs    = (float*)(ws + OFF_HS);
    float*    EMB   = (float*)(ws + OFF_EMB);

    const int* srcp = ei;
    const int* dstp = ei + Ee;

    const int scanBlocks = 782;   // grid-stride over Ee/4 quads, ~8 edges/thread

    k_zero  <<<512, 256, 0, stream>>>((float4*)ws, (int)(ZERO_BYTES / 16));
    k_scanT <<<scanBlocks, 256, 0, stream>>>(srcp, dstp, cur, des, nbr, hdr, markS, L2);
    k_stageC<<<(Nn / 4 + 255) / 256, 256, 0, stream>>>(markS, hdr, Slist, bmS);
    k_scanS <<<scanBlocks, 256, 0, stream>>>(srcp, dstp, markS, bmS, hdr, L1);
    k_aggr  <<<CAP1 * 32 / 256, 256, 0, stream>>>(x, ea, We1, be1, L1, hdr,
                                                  HDR_CNTL1, CAP1, nullptr, A1);
    k_mlpS  <<<CAPS, 128, 0, stream>>>(x, A1, Slist, hdr, W11, b11, W12, b12, Hs);
    k_aggr  <<<CAP2 * 32 / 256, 256, 0, stream>>>(Hs, ea, We2, be2, L2, hdr,
                                                  HDR_CNTL2, CAP2, markS, A2);
    k_mlpT  <<<NT, 128, 0, stream>>>(Hs, A2, cur, des, nbr, markS,
                                     W21, b21, W22, b22, EMB);
    k_policy<<<16, 512, 0, stream>>>(EMB, cur, des, nbr, Wl1, bl1, Wl2, bl2, out);
}

// Round 6
// 64.420 us; speedup vs baseline: 1.7134x; 1.7134x over previous
//
#include <hip/hip_runtime.h>

// Problem constants (fixed by the reference harness).
constexpr int Nn   = 100000;   // nodes
constexpr int Ee   = 1600000;  // edges  (divisible by 4)
constexpr int D    = 128;      // feature dim
constexpr int NT   = 18;       // 2 + 16 target entries (duplicates allowed)

// Capacities (expected: |L2|~290, |S|~310, |L1|~5000)
constexpr int CAPS = 1024;
constexpr int CAP2 = 1024;
constexpr int CAP1 = 8192;

constexpr int BMW = 3136;      // bitmap words: >= ceil(Nn/32)=3125, %4==0
constexpr int LOC = 128;       // per-block LDS staging capacity (hits)

// hdr slots
#define HDR_CNTS  1
#define HDR_CNTL1 2
#define HDR_CNTL2 3

// ---- workspace byte offsets (all 16B aligned) ----
constexpr size_t OFF_HDR   = 0;          // int[64]          256   (zeroed)
constexpr size_t OFF_MARKS = 256;        // int[Nn]          400000
constexpr size_t OFF_BMS   = 400256;     // u32[BMW]         12544
constexpr size_t OFF_A1    = 412800;     // f32[CAPS*D]      524288
constexpr size_t OFF_A2    = 937088;     // f32[32*D]        16384
constexpr size_t ZERO_BYTES= 953472;     // zero everything above (÷16 ok)
constexpr size_t OFF_SLIST = 953472;     // int[CAPS]        4096
constexpr size_t OFF_L2    = 957568;     // int[CAP2*3]      12288
constexpr size_t OFF_L1    = 969856;     // int[CAP1*3]      98304
constexpr size_t OFF_HS    = 1068160;    // f32[CAPS*D]      524288
constexpr size_t OFF_EMB   = 1592448;    // f32[32*D]        16384
constexpr size_t WS_NEED   = 1608832;

__global__ void k_zero(float4* p, int n4) {
    int i = blockIdx.x * blockDim.x + threadIdx.x;
    int stride = gridDim.x * blockDim.x;
    for (; i < n4; i += stride) p[i] = float4{0.f, 0.f, 0.f, 0.f};
}

// Scan all edges; per-block LDS bitmap of the 18 target ids for the membership
// test. Hits are staged in LDS; ONE global atomicAdd per block reserves the
// L2-list range (contended same-address atomics were the R3/R4 bottleneck).
__global__ void __launch_bounds__(256)
k_scanT(const int* __restrict__ src, const int* __restrict__ dst,
        const int* __restrict__ cur, const int* __restrict__ des,
        const int* __restrict__ nbr,
        int* __restrict__ hdr, int* __restrict__ markS, int* __restrict__ L2) {
    __shared__ unsigned bm[BMW];
    __shared__ int sT[NT];
    __shared__ int loc[LOC * 3];
    __shared__ int lcnt, lbase;
    int t = threadIdx.x;
    if (t == 0) lcnt = 0;
    for (int w = t; w < BMW; w += 256) bm[w] = 0u;
    if (t < NT) {
        int v = (t == 0) ? cur[0] : (t == 1) ? des[0] : nbr[t - 2];
        sT[t] = v;
        if (blockIdx.x == 0) markS[v] = 1;   // targets need h too
    }
    __syncthreads();
    if (t < NT) atomicOr(&bm[(unsigned)sT[t] >> 5], 1u << (sT[t] & 31));
    __syncthreads();
    int stride = gridDim.x * blockDim.x;
    for (int q = blockIdx.x * blockDim.x + t; q < Ee / 4; q += stride) {
        int4 d4 = reinterpret_cast<const int4*>(dst)[q];
        int ds[4] = {d4.x, d4.y, d4.z, d4.w};
        #pragma unroll
        for (int j = 0; j < 4; ++j) {
            int d = ds[j];
            if ((bm[(unsigned)d >> 5] >> (d & 31)) & 1u) {
                int slot = 0;
                while (sT[slot] != d) ++slot;   // first occurrence, always found
                int e = q * 4 + j;
                int s = src[e];
                markS[s] = 1;  // benign same-value race
                int li = atomicAdd(&lcnt, 1);
                if (li < LOC) {
                    loc[3*li] = s; loc[3*li+1] = e; loc[3*li+2] = slot;
                } else {  // overflow fallback (statistically never taken)
                    int idx = atomicAdd(&hdr[HDR_CNTL2], 1);
                    if (idx < CAP2) { L2[3*idx] = s; L2[3*idx+1] = e; L2[3*idx+2] = slot; }
                }
            }
        }
    }
    __syncthreads();
    if (t == 0) {
        int n = lcnt < LOC ? lcnt : LOC;
        lbase = n ? atomicAdd(&hdr[HDR_CNTL2], n) : 0;
        lcnt = n;
    }
    __syncthreads();
    for (int i = t; i < lcnt; i += 256) {
        int idx = lbase + i;
        if (idx < CAP2) {
            L2[3*idx] = loc[3*i]; L2[3*idx+1] = loc[3*i+1]; L2[3*idx+2] = loc[3*i+2];
        }
    }
}

// Assign compact slots to marked nodes (markS: 1 -> 2+slot); build global
// S-bitmap. Block-staged: one global reservation atomic per block.
__global__ void __launch_bounds__(256)
k_stageC(int* __restrict__ markS, int* __restrict__ hdr,
         int* __restrict__ Slist, unsigned* __restrict__ bmS) {
    __shared__ int loc[256];
    __shared__ int lcnt, lbase;
    int t = threadIdx.x;
    if (t == 0) lcnt = 0;
    __syncthreads();
    int i = blockIdx.x * blockDim.x + t;
    if (i < Nn / 4) {
        int4 m4 = reinterpret_cast<const int4*>(markS)[i];
        int ms[4] = {m4.x, m4.y, m4.z, m4.w};
        int v0 = i * 4;
        #pragma unroll
        for (int j = 0; j < 4; ++j) {
            if (ms[j] == 1) {
                int li = atomicAdd(&lcnt, 1);
                if (li < 256) loc[li] = v0 + j;
                else {  // overflow fallback
                    int s = atomicAdd(&hdr[HDR_CNTS], 1);
                    if (s < CAPS) {
                        int v = v0 + j;
                        markS[v] = 2 + s; Slist[s] = v;
                        atomicOr(&bmS[(unsigned)v >> 5], 1u << (v & 31));
                    }
                }
            }
        }
    }
    __syncthreads();
    if (t == 0) {
        int n = lcnt < 256 ? lcnt : 256;
        lbase = n ? atomicAdd(&hdr[HDR_CNTS], n) : 0;
        lcnt = n;
    }
    __syncthreads();
    if (t < lcnt) {
        int s = lbase + t;
        if (s < CAPS) {
            int v = loc[t];
            markS[v] = 2 + s;
            Slist[s] = v;
            atomicOr(&bmS[(unsigned)v >> 5], 1u << (v & 31));
        }
    }
}

// Scan all edges; membership test against LDS copy of the S-bitmap. Hits
// staged in LDS; one global reservation atomic per block.
__global__ void __launch_bounds__(256)
k_scanS(const int* __restrict__ src, const int* __restrict__ dst,
        const int* __restrict__ markS, const unsigned* __restrict__ bmS,
        int* __restrict__ hdr, int* __restrict__ L1) {
    __shared__ unsigned bm[BMW];
    __shared__ int loc[LOC * 3];
    __shared__ int lcnt, lbase;
    int t = threadIdx.x;
    if (t == 0) lcnt = 0;
    const uint4* g = reinterpret_cast<const uint4*>(bmS);
    for (int w = t; w < BMW / 4; w += 256) reinterpret_cast<uint4*>(bm)[w] = g[w];
    __syncthreads();
    int stride = gridDim.x * blockDim.x;
    for (int q = blockIdx.x * blockDim.x + t; q < Ee / 4; q += stride) {
        int4 d4 = reinterpret_cast<const int4*>(dst)[q];
        int ds[4] = {d4.x, d4.y, d4.z, d4.w};
        #pragma unroll
        for (int j = 0; j < 4; ++j) {
            int d = ds[j];
            if ((bm[(unsigned)d >> 5] >> (d & 31)) & 1u) {
                int e = q * 4 + j;
                int v = markS[d];
                if (v >= 2) {
                    int li = atomicAdd(&lcnt, 1);
                    if (li < LOC) {
                        loc[3*li] = src[e]; loc[3*li+1] = e; loc[3*li+2] = v - 2;
                    } else {  // overflow fallback
                        int idx = atomicAdd(&hdr[HDR_CNTL1], 1);
                        if (idx < CAP1) { L1[3*idx] = src[e]; L1[3*idx+1] = e; L1[3*idx+2] = v - 2; }
                    }
                }
            }
        }
    }
    __syncthreads();
    if (t == 0) {
        int n = lcnt < LOC ? lcnt : LOC;
        lbase = n ? atomicAdd(&hdr[HDR_CNTL1], n) : 0;
        lcnt = n;
    }
    __syncthreads();
    for (int i = t; i < lcnt; i += 256) {
        int idx = lbase + i;
        if (idx < CAP1) {
            L1[3*idx] = loc[3*i]; L1[3*idx+1] = loc[3*i+1]; L1[3*idx+2] = loc[3*i+2];
        }
    }
}

// Aggregate messages: A[slot][d] += relu(X[row][d] + ea[e]*We[d] + be[d]).
// If remap != null, row = remap[src]-2 (compacted Hs rows), else row = src.
__global__ void k_aggr(const float* __restrict__ X, const float* __restrict__ ea,
                       const float* __restrict__ We, const float* __restrict__ be,
                       const int* __restrict__ L, int* __restrict__ hdr,
                       int cntIdx, int cap, const int* __restrict__ remap,
                       float* __restrict__ A) {
    int tid = blockIdx.x * blockDim.x + threadIdx.x;
    int i = tid >> 5;  // 32 threads per edge, 4 dims each
    int cnt = hdr[cntIdx];
    if (cnt > cap) cnt = cap;
    if (i >= cnt) return;
    int s    = L[3*i + 0];
    int e    = L[3*i + 1];
    int slot = L[3*i + 2];
    if (remap) {
        s = remap[s] - 2;
        if ((unsigned)s >= (unsigned)CAPS) return;
    }
    int d0 = (tid & 31) << 2;
    float a = ea[e];
    float4 xv = *reinterpret_cast<const float4*>(&X[(size_t)s * D + d0]);
    float4 wv = *reinterpret_cast<const float4*>(&We[d0]);
    float4 bv = *reinterpret_cast<const float4*>(&be[d0]);
    float* Ar = &A[(size_t)slot * D + d0];
    atomicAdd(Ar + 0, fmaxf(fmaf(a, wv.x, bv.x) + xv.x, 0.f));
    atomicAdd(Ar + 1, fmaxf(fmaf(a, wv.y, bv.y) + xv.y, 0.f));
    atomicAdd(Ar + 2, fmaxf(fmaf(a, wv.z, bv.z) + xv.z, 0.f));
    atomicAdd(Ar + 3, fmaxf(fmaf(a, wv.w, bv.w) + xv.w, 0.f));
}

// conv1 MLP per S-node: Hs[b] = relu( relu((x[node]+A1[b])@W1 + b1) @ W2 + b2 )
__global__ void k_mlpS(const float* __restrict__ x, const float* __restrict__ A,
                       const int* __restrict__ Slist, const int* __restrict__ hdr,
                       const float* __restrict__ W1, const float* __restrict__ b1,
                       const float* __restrict__ W2, const float* __restrict__ b2,
                       float* __restrict__ Hs) {
    __shared__ float buf[D];
    __shared__ float hid[D];
    int b = blockIdx.x;
    int cnt = hdr[HDR_CNTS];
    if (cnt > CAPS) cnt = CAPS;
    if (b >= cnt) return;
    int t = threadIdx.x;  // 128 threads
    int node = Slist[b];
    buf[t] = x[(size_t)node * D + t] + A[(size_t)b * D + t];
    __syncthreads();
    float acc = b1[t];
    #pragma unroll 8
    for (int k = 0; k < D; ++k) acc = fmaf(buf[k], W1[k * D + t], acc);
    hid[t] = fmaxf(acc, 0.f);
    __syncthreads();
    float acc2 = b2[t];
    #pragma unroll 8
    for (int k = 0; k < D; ++k) acc2 = fmaf(hid[k], W2[k * D + t], acc2);
    Hs[(size_t)b * D + t] = fmaxf(acc2, 0.f);
}

// conv2 MLP per target entry (first-occurrence only):
// EMB[b] = relu((Hs[slot]+A2[b])@W1 + b1) @ W2 + b2
__global__ void k_mlpT(const float* __restrict__ Hs, const float* __restrict__ A2,
                       const int* __restrict__ cur, const int* __restrict__ des,
                       const int* __restrict__ nbr, const int* __restrict__ markS,
                       const float* __restrict__ W1, const float* __restrict__ b1,
                       const float* __restrict__ W2, const float* __restrict__ b2,
                       float* __restrict__ EMB) {
    __shared__ float buf[D];
    __shared__ float hid[D];
    __shared__ int sT[NT];
    int b = blockIdx.x;      // 0..17
    int t = threadIdx.x;     // 128 threads
    if (t < NT) sT[t] = (t == 0) ? cur[0] : (t == 1) ? des[0] : nbr[t - 2];
    __syncthreads();
    int node = sT[b];
    for (int j = 0; j < b; ++j) if (sT[j] == node) return;  // duplicate entry
    int ss = markS[node] - 2;
    if ((unsigned)ss >= (unsigned)CAPS) return;
    buf[t] = Hs[(size_t)ss * D + t] + A2[(size_t)b * D + t];
    __syncthreads();
    float acc = b1[t];
    #pragma unroll 8
    for (int k = 0; k < D; ++k) acc = fmaf(buf[k], W1[k * D + t], acc);
    hid[t] = fmaxf(acc, 0.f);
    __syncthreads();
    float acc2 = b2[t];
    #pragma unroll 8
    for (int k = 0; k < D; ++k) acc2 = fmaf(hid[k], W2[k * D + t], acc2);
    EMB[(size_t)b * D + t] = acc2;  // no final relu
}

// Policy head: one block per neighbor k; 512 threads = 4-way split of the
// 384-long dot product, LDS-reduced.
__global__ void __launch_bounds__(512)
k_policy(const float* __restrict__ EMB,
         const int* __restrict__ cur, const int* __restrict__ des,
         const int* __restrict__ nbr,
         const float* __restrict__ Wl1, const float* __restrict__ bl1,
         const float* __restrict__ Wl2, const float* __restrict__ bl2,
         float* __restrict__ out) {
    __shared__ int sT[NT];
    __shared__ float cat[3 * D];
    __shared__ float part[4][D];
    __shared__ float red[D];
    int tid = threadIdx.x;
    int k = blockIdx.x;  // 0..15
    if (tid < NT) sT[tid] = (tid == 0) ? cur[0] : (tid == 1) ? des[0] : nbr[tid - 2];
    __syncthreads();
    // first-occurrence slots (must match k_scanT / k_mlpT semantics)
    int dsl = (sT[1] == sT[0]) ? 0 : 1;
    int nn = sT[2 + k];
    int nsl = 2 + k;
    for (int j = 0; j < 2 + k; ++j) if (sT[j] == nn) { nsl = j; break; }
    if (tid < 3 * D) {
        int seg = tid >> 7;             // 0=curr, 1=dest, 2=nbr
        int t = tid & (D - 1);
        int slot = (seg == 0) ? 0 : (seg == 1) ? dsl : nsl;
        cat[tid] = EMB[slot * D + t];
    }
    __syncthreads();
    int h = tid >> 7;        // 0..3
    int t = tid & (D - 1);
    float acc = 0.f;
    int c0 = h * 96;
    #pragma unroll 8
    for (int c = c0; c < c0 + 96; ++c)
        acc = fmaf(cat[c], Wl1[c * D + t], acc);
    part[h][t] = acc;
    __syncthreads();
    if (tid < D) {
        float v = part[0][t] + part[1][t] + part[2][t] + part[3][t] + bl1[t];
        red[t] = fmaxf(v, 0.f) * Wl2[t];
    }
    __syncthreads();
    for (int s = 64; s > 0; s >>= 1) {
        if (tid < s) red[tid] += red[tid + s];
        __syncthreads();
    }
    if (tid == 0) out[k] = red[0] + bl2[0];
}

extern "C" void kernel_launch(void* const* d_in, const int* in_sizes, int n_in,
                              void* d_out, int out_size, void* d_ws, size_t ws_size,
                              hipStream_t stream) {
    if (ws_size < WS_NEED) return;  // safety guard

    const float* x   = (const float*)d_in[0];
    const int*   ei  = (const int*)d_in[1];   // (2,E) row-major int32
    const int*   cur = (const int*)d_in[2];
    const int*   des = (const int*)d_in[3];
    const int*   nbr = (const int*)d_in[4];
    const float* ea  = (const float*)d_in[5]; // (E,1)
    const float* We1 = (const float*)d_in[6];
    const float* be1 = (const float*)d_in[7];
    const float* W11 = (const float*)d_in[8];
    const float* b11 = (const float*)d_in[9];
    const float* W12 = (const float*)d_in[10];
    const float* b12 = (const float*)d_in[11];
    const float* We2 = (const float*)d_in[12];
    const float* be2 = (const float*)d_in[13];
    const float* W21 = (const float*)d_in[14];
    const float* b21 = (const float*)d_in[15];
    const float* W22 = (const float*)d_in[16];
    const float* b22 = (const float*)d_in[17];
    const float* Wl1 = (const float*)d_in[18];
    const float* bl1 = (const float*)d_in[19];
    const float* Wl2 = (const float*)d_in[20];
    const float* bl2 = (const float*)d_in[21];
    float* out = (float*)d_out;

    char*     ws    = (char*)d_ws;
    int*      hdr   = (int*)(ws + OFF_HDR);
    int*      markS = (int*)(ws + OFF_MARKS);
    unsigned* bmS   = (unsigned*)(ws + OFF_BMS);
    float*    A1    = (float*)(ws + OFF_A1);
    float*    A2    = (float*)(ws + OFF_A2);
    int*      Slist = (int*)(ws + OFF_SLIST);
    int*      L2    = (int*)(ws + OFF_L2);
    int*      L1    = (int*)(ws + OFF_L1);
    float*    Hs    = (float*)(ws + OFF_HS);
    float*    EMB   = (float*)(ws + OFF_EMB);

    const int* srcp = ei;
    const int* dstp = ei + Ee;

    const int scanBlocks = 256;   // grid-stride; ~6 quads/thread, 1 reservation atomic/block

    k_zero  <<<512, 256, 0, stream>>>((float4*)ws, (int)(ZERO_BYTES / 16));
    k_scanT <<<scanBlocks, 256, 0, stream>>>(srcp, dstp, cur, des, nbr, hdr, markS, L2);
    k_stageC<<<(Nn / 4 + 255) / 256, 256, 0, stream>>>(markS, hdr, Slist, bmS);
    k_scanS <<<scanBlocks, 256, 0, stream>>>(srcp, dstp, markS, bmS, hdr, L1);
    k_aggr  <<<CAP1 * 32 / 256, 256, 0, stream>>>(x, ea, We1, be1, L1, hdr,
                                                  HDR_CNTL1, CAP1, nullptr, A1);
    k_mlpS  <<<CAPS, 128, 0, stream>>>(x, A1, Slist, hdr, W11, b11, W12, b12, Hs);
    k_aggr  <<<CAP2 * 32 / 256, 256, 0, stream>>>(Hs, ea, We2, be2, L2, hdr,
                                                  HDR_CNTL2, CAP2, markS, A2);
    k_mlpT  <<<NT, 128, 0, stream>>>(Hs, A2, cur, des, nbr, markS,
                                     W21, b21, W22, b22, EMB);
    k_policy<<<16, 512, 0, stream>>>(EMB, cur, des, nbr, Wl1, bl1, Wl2, bl2, out);
}